// Round 17
// baseline (63.548 us; speedup 1.0000x reference)
//
#include <hip/hip_runtime.h>

namespace {
constexpr int BB = 2;
constexpr int NN = 50000;
constexpr int KK = 16;
constexpr int CI = 64;
constexpr int CO = 32;
constexpr int MM = 4;
constexpr int BN = BB * NN;     // 100000 nodes
constexpr int GROUPS = NN / 4;  // 12500 4-node groups per batch
constexpr int GRID = 768;       // 3 blocks/CU (36.9KB LDS)
constexpr int WAVES = (GRID / 2) * 4;  // 1536 waves per batch
}

typedef __attribute__((ext_vector_type(8))) short short8v;
typedef __attribute__((ext_vector_type(4))) float float4v;
typedef __attribute__((ext_vector_type(2))) float f32x2;

union F4P {
  float4 f4;
  f32x2 p[2];
};

__device__ __forceinline__ unsigned short bf16r(float f) {
  unsigned int u = __float_as_uint(f);
  u += 0x7FFFu + ((u >> 16) & 1u);
  return (unsigned short)(u >> 16);
}

// K1: wave-per-16-node tile. Coalesced x loads; ux/vx via 2 MFMAs against
// [u;v] B-fragment; bf16 xh written from the same registers.
__global__ __launch_bounds__(256) void k_prep2(
    const float* __restrict__ x, const float* __restrict__ u,
    const float* __restrict__ v, float* __restrict__ ux,
    float* __restrict__ vx, unsigned short* __restrict__ xh) {
  const int tid = threadIdx.x;
  const int lane = tid & 63;
  const int wv = tid >> 6;
  const int col = lane & 15;
  const int krow = lane >> 4;

  short8v bfrag2[2];
#pragma unroll
  for (int ks = 0; ks < 2; ++ks)
#pragma unroll
    for (int e = 0; e < 8; ++e) {
      int c = ks * 32 + krow * 8 + e;
      float val = (col < 4) ? u[col * CI + c]
                            : ((col < 8) ? v[(col - 4) * CI + c] : 0.f);
      bfrag2[ks][e] = (short)bf16r(val);
    }

  const float4v zero = {0.f, 0.f, 0.f, 0.f};
  const int nw = gridDim.x * 4;
  for (int t = blockIdx.x * 4 + wv; t < BN / 16; t += nw) {
    const int n0 = t * 16;
    const float* xp = x + (size_t)(n0 + col) * CI + krow * 8;
    short8v afrag[2];
    uint4 hpack[2];
#pragma unroll
    for (int ks = 0; ks < 2; ++ks) {
      float4 lo = *(const float4*)(xp + ks * 32);
      float4 hi = *(const float4*)(xp + ks * 32 + 4);
      unsigned short h0 = bf16r(lo.x), h1 = bf16r(lo.y);
      unsigned short h2 = bf16r(lo.z), h3 = bf16r(lo.w);
      unsigned short h4 = bf16r(hi.x), h5 = bf16r(hi.y);
      unsigned short h6 = bf16r(hi.z), h7 = bf16r(hi.w);
      afrag[ks][0] = (short)h0;
      afrag[ks][1] = (short)h1;
      afrag[ks][2] = (short)h2;
      afrag[ks][3] = (short)h3;
      afrag[ks][4] = (short)h4;
      afrag[ks][5] = (short)h5;
      afrag[ks][6] = (short)h6;
      afrag[ks][7] = (short)h7;
      hpack[ks] = make_uint4((unsigned)h0 | ((unsigned)h1 << 16),
                             (unsigned)h2 | ((unsigned)h3 << 16),
                             (unsigned)h4 | ((unsigned)h5 << 16),
                             (unsigned)h6 | ((unsigned)h7 << 16));
    }
    unsigned short* xo = xh + (size_t)(n0 + col) * CI + krow * 8;
    *(uint4*)(xo) = hpack[0];
    *(uint4*)(xo + 32) = hpack[1];

    float4v acc2 = zero;
    acc2 = __builtin_amdgcn_mfma_f32_16x16x32_bf16(afrag[0], bfrag2[0], acc2,
                                                   0, 0, 0);
    acc2 = __builtin_amdgcn_mfma_f32_16x16x32_bf16(afrag[1], bfrag2[1], acc2,
                                                   0, 0, 0);
#pragma unroll
    for (int ri = 0; ri < 4; ++ri) {
      int node = n0 + krow * 4 + ri;
      if (col < 4)
        ux[(size_t)node * MM + col] = acc2[ri];
      else if (col < 8)
        vx[(size_t)node * MM + (col - 4)] = acc2[ri];
    }
  }
}

// K2: gather with ASM-PINNED loads (73 VMEM in flight per wave) + softmax +
// packed-FMA t-accumulate + MFMA W-matmul. Deg-norm folded into q.
__global__ __launch_bounds__(256, 3) void k_gather(
    const unsigned short* __restrict__ xh, const int* __restrict__ adj,
    const float* __restrict__ weight, const float* __restrict__ bias,
    const float* __restrict__ cvec, const float* __restrict__ ux,
    const float* __restrict__ vx, float* __restrict__ out) {
  __shared__ unsigned short w_lds[2 * 8 * 64 * 8];  // 16 KB B-fragments
  __shared__ unsigned short t_lds[4][8 * 256];      // 16 KB A rows per wave
  __shared__ float q_lds[4][4][64];                 // 4 KB

  const int tid = threadIdx.x;
  const int lane = tid & 63;
  const int wv = tid >> 6;

  // Stage W as MFMA B-fragments (k = c*4+m ordering, o = tl*16+(l&15))
  for (int i = tid; i < 2 * 8 * 64; i += 256) {
    int tl = i >> 9;
    int ks = (i >> 6) & 7;
    int l = i & 63;
    int o = tl * 16 + (l & 15);
    unsigned pk[4];
#pragma unroll
    for (int ee = 0; ee < 4; ++ee) {
      int k0 = ks * 32 + (l >> 4) * 8 + 2 * ee;
      unsigned lo = bf16r(weight[((k0 & 3) * CO + o) * CI + (k0 >> 2)]);
      unsigned hi =
          bf16r(weight[(((k0 + 1) & 3) * CO + o) * CI + ((k0 + 1) >> 2)]);
      pk[ee] = lo | (hi << 16);
    }
    *(uint4*)&w_lds[i * 8] = make_uint4(pk[0], pk[1], pk[2], pk[3]);
  }
  __syncthreads();

  const int m4 = lane & 3;
  const int k4 = lane >> 2;
  const float cm = cvec[m4];
  const float b0 = bias[lane & 15];
  const float b1 = bias[16 + (lane & 15)];
  const unsigned voff2 = (unsigned)lane * 2u;  // shared gather voffset

  // XCD partition: XCDs 0-3 -> batch 0, 4-7 -> batch 1
  const int xcd = blockIdx.x & 7;
  const int b = xcd >> 2;
  const int wb = ((blockIdx.x >> 3) << 2) | (xcd & 3);
  const int w = wb * 4 + wv;
  const size_t bbase = (size_t)b * NN;
  const unsigned short* xhb = xh + bbase * CI;
  const float* vxb = vx + bbase * MM;
  unsigned short* twv = t_lds[wv];

// asm-pinned gather: saddr in SGPRs (readlane row), shared VGPR voffset.
// asm volatile blocks are mutually ordered and opaque to waitcnt insertion:
// all 16 issue back-to-back and stay in flight.
#define LOADS(n, GV)                                                       \
  _Pragma("unroll") for (int k = 0; k < KK; ++k) {                         \
    int r = __builtin_amdgcn_readlane(av_c, (n)*16 + k);                   \
    const unsigned short* rp = xhb + (size_t)(max(r, 1) - 1) * CI;         \
    asm volatile("global_load_ushort %0, %1, %2"                           \
                 : "=v"(GV[k])                                             \
                 : "v"(voff2), "s"(rp)                                     \
                 : "memory");                                              \
  }

// asm per-lane dword load (64-bit vaddr)
#define GLOADF(dst, ptr)                                                   \
  asm volatile("global_load_dword %0, %1, off"                             \
               : "=v"(dst)                                                 \
               : "v"(ptr)                                                  \
               : "memory");
#define GLOADF_OFF(dst, ptr, imm)                                          \
  asm volatile("global_load_dword %0, %1, off offset:" #imm                \
               : "=v"(dst)                                                 \
               : "v"(ptr)                                                  \
               : "memory");

#define ACC_NODE(n, GV)                                                    \
  {                                                                        \
    const float4* qp = (const float4*)&q_lds[wv][n][0];                    \
    f32x2 t01 = {0.f, 0.f}, t23 = {0.f, 0.f};                              \
    _Pragma("unroll") for (int k = 0; k < KK; ++k) {                       \
      float xv = __uint_as_float(GV[k] << 16);                             \
      F4P qv;                                                              \
      qv.f4 = qp[k];                                                       \
      t01 += qv.p[0] * xv;                                                 \
      t23 += qv.p[1] * xv;                                                 \
    }                                                                      \
    unsigned lo, hi;                                                       \
    asm("v_cvt_pk_bf16_f32 %0, %1, %2"                                     \
        : "=v"(lo)                                                         \
        : "v"(t01[0]), "v"(t01[1]));                                       \
    asm("v_cvt_pk_bf16_f32 %0, %1, %2"                                     \
        : "=v"(hi)                                                         \
        : "v"(t23[0]), "v"(t23[1]));                                       \
    int row = jrows * 4 + (n);                                             \
    unsigned boff = (unsigned)row * 512u +                                 \
                    (((unsigned)lane * 8u) ^ ((unsigned)(row & 7) << 4));  \
    *(uint2*)((char*)twv + boff) = make_uint2(lo, hi);                     \
  }

#define FLUSH(JC)                                                          \
  {                                                                        \
    float4v ac0 = {0.f, 0.f, 0.f, 0.f};                                    \
    float4v ac1 = {0.f, 0.f, 0.f, 0.f};                                    \
    const int arow = lane & 7;                                             \
    const unsigned axor = (unsigned)(arow & 7) << 4;                       \
    _Pragma("unroll") for (int ks = 0; ks < 8; ++ks) {                     \
      unsigned aoff =                                                      \
          (unsigned)arow * 512u +                                          \
          ((((unsigned)(lane >> 4)) * 16u + (unsigned)ks * 64u) ^ axor);   \
      short8v A = *(const short8v*)((const char*)twv + aoff);              \
      short8v Bl = *(const short8v*)&w_lds[(0 * 8 + ks) * 512 + lane * 8]; \
      short8v Bh = *(const short8v*)&w_lds[(1 * 8 + ks) * 512 + lane * 8]; \
      ac0 = __builtin_amdgcn_mfma_f32_16x16x32_bf16(A, Bl, ac0, 0, 0, 0);  \
      ac1 = __builtin_amdgcn_mfma_f32_16x16x32_bf16(A, Bh, ac1, 0, 0, 0);  \
    }                                                                      \
    int jj = lane >> 4;                                                    \
    int gg = gbase + jj * WAVES;                                           \
    if (jj < (JC) && gg < GROUPS) {                                        \
      float* op = out + (bbase + (size_t)gg * 4) * CO + (lane & 15);       \
      op[0] = ac0[0] + b0;                                                 \
      op[16] = ac1[0] + b1;                                                \
      op[32] = ac0[1] + b0;                                                \
      op[48] = ac1[1] + b1;                                                \
      op[64] = ac0[2] + b0;                                                \
      op[80] = ac1[2] + b1;                                                \
      op[96] = ac0[3] + b0;                                                \
      op[112] = ac1[3] + b1;                                               \
    }                                                                      \
  }

  int g = w;
  int av = 0;
  if (g < GROUPS) av = adj[(bbase + (size_t)g * 4) * KK + lane];
  int jrows = 0;
  int gbase = g;

  while (g < GROUPS) {
    const int av_c = av;
    const size_t bn0 = bbase + (size_t)g * 4;

    // softmax-side addresses (data-dependent), then ISSUE EVERYTHING:
    int as0 = __shfl(av_c, k4);
    int as1 = __shfl(av_c, 16 + k4);
    int as2 = __shfl(av_c, 32 + k4);
    int as3 = __shfl(av_c, 48 + k4);
    float vg0, vg1, vg2, vg3, ux0, ux1, ux2, ux3;
    {
      const float* vp0 = vxb + (size_t)(max(as0, 1) - 1) * MM + m4;
      const float* vp1 = vxb + (size_t)(max(as1, 1) - 1) * MM + m4;
      const float* vp2 = vxb + (size_t)(max(as2, 1) - 1) * MM + m4;
      const float* vp3 = vxb + (size_t)(max(as3, 1) - 1) * MM + m4;
      const float* up = ux + bn0 * MM + m4;
      GLOADF(vg0, vp0)
      GLOADF(vg1, vp1)
      GLOADF(vg2, vp2)
      GLOADF(vg3, vp3)
      GLOADF_OFF(ux0, up, 0)
      GLOADF_OFF(ux1, up, 16)
      GLOADF_OFF(ux2, up, 32)
      GLOADF_OFF(ux3, up, 48)
    }

    unsigned gv0[KK], gv1[KK], gv2[KK], gv3[KK];
    LOADS(0, gv0)
    LOADS(1, gv1)
    LOADS(2, gv2)
    LOADS(3, gv3)

    // adjacency for next group (last in issue order -> vmcnt(1) spares it)
    const int gn = g + WAVES;
    {
      const int gnc = (gn < GROUPS) ? gn : g;
      const int* ap = adj + (bbase + (size_t)gnc * 4) * KK + lane;
      GLOADF(av, ap)
    }

    const unsigned long long msk = __ballot(av_c != 0);

    // wait for all but the adj load; fence against hoisting (rule #18)
    asm volatile("s_waitcnt vmcnt(1)" ::: "memory");
    __builtin_amdgcn_sched_barrier(0);

    // softmax for 4 nodes; deg-norm folded into q
    {
      int d0 = __popc((unsigned)(msk & 0xFFFFull));
      int d1 = __popc((unsigned)((msk >> 16) & 0xFFFFull));
      int d2 = __popc((unsigned)((msk >> 32) & 0xFFFFull));
      int d3 = __popc((unsigned)((msk >> 48) & 0xFFFFull));
      float i0 = d0 ? __builtin_amdgcn_rcpf((float)d0) : 0.f;
      float i1 = d1 ? __builtin_amdgcn_rcpf((float)d1) : 0.f;
      float i2 = d2 ? __builtin_amdgcn_rcpf((float)d2) : 0.f;
      float i3 = d3 ? __builtin_amdgcn_rcpf((float)d3) : 0.f;
      float e0 = __expf(vg0 + ux0 + cm);
      float e1 = __expf(vg1 + ux1 + cm);
      float e2 = __expf(vg2 + ux2 + cm);
      float e3 = __expf(vg3 + ux3 + cm);
      float s0 = e0 + __shfl_xor(e0, 1);
      float s1 = e1 + __shfl_xor(e1, 1);
      float s2 = e2 + __shfl_xor(e2, 1);
      float s3 = e3 + __shfl_xor(e3, 1);
      s0 += __shfl_xor(s0, 2);
      s1 += __shfl_xor(s1, 2);
      s2 += __shfl_xor(s2, 2);
      s3 += __shfl_xor(s3, 2);
      q_lds[wv][0][lane] =
          (as0 != 0) ? e0 * __builtin_amdgcn_rcpf(s0) * i0 : 0.f;
      q_lds[wv][1][lane] =
          (as1 != 0) ? e1 * __builtin_amdgcn_rcpf(s1) * i1 : 0.f;
      q_lds[wv][2][lane] =
          (as2 != 0) ? e2 * __builtin_amdgcn_rcpf(s2) * i2 : 0.f;
      q_lds[wv][3][lane] =
          (as3 != 0) ? e3 * __builtin_amdgcn_rcpf(s3) * i3 : 0.f;
    }
    // same-wave DS write->read is in-order: no barrier needed

    ACC_NODE(0, gv0)
    ACC_NODE(1, gv1)
    ACC_NODE(2, gv2)
    ACC_NODE(3, gv3)

    ++jrows;
    g = gn;
    if (jrows == 2) {
      FLUSH(2)
      jrows = 0;
      gbase = g;
    }
  }
  if (jrows > 0) FLUSH(jrows)
}

// ---------- fallback path (ws too small): all-fp32 ----------
__global__ __launch_bounds__(256) void k_uxvx(
    const float* __restrict__ x, const float* __restrict__ u,
    const float* __restrict__ v, float* __restrict__ ux,
    float* __restrict__ vx) {
  int idx = blockIdx.x * 256 + threadIdx.x;
  if (idx >= BN) return;
  const float4* xr = (const float4*)(x + (size_t)idx * CI);
  float su[MM] = {0.f, 0.f, 0.f, 0.f};
  float sv[MM] = {0.f, 0.f, 0.f, 0.f};
#pragma unroll
  for (int t = 0; t < CI / 4; ++t) {
    float4 xv = xr[t];
#pragma unroll
    for (int m = 0; m < MM; ++m) {
      float4 uv = *(const float4*)(u + m * CI + t * 4);
      float4 vv = *(const float4*)(v + m * CI + t * 4);
      su[m] += uv.x * xv.x + uv.y * xv.y + uv.z * xv.z + uv.w * xv.w;
      sv[m] += vv.x * xv.x + vv.y * xv.y + vv.z * xv.z + vv.w * xv.w;
    }
  }
  ((float4*)ux)[idx] = make_float4(su[0], su[1], su[2], su[3]);
  ((float4*)vx)[idx] = make_float4(sv[0], sv[1], sv[2], sv[3]);
}

__global__ __launch_bounds__(256) void k_main_old(
    const float* __restrict__ x, const int* __restrict__ adj,
    const float* __restrict__ weight, const float* __restrict__ bias,
    const float* __restrict__ cvec, const float* __restrict__ ux,
    const float* __restrict__ vx, float* __restrict__ out) {
  __shared__ float w_lds2[MM][CO][CI + 4];
  __shared__ float q_lds2[4][64];
  __shared__ float t_lds2[4][MM][CI];
  const int tid = threadIdx.x;
  const int lane = tid & 63;
  const int wv = tid >> 6;
#pragma unroll
  for (int i = 0; i < (MM * CO * CI) / 256; ++i) {
    int g = i * 256 + tid;
    w_lds2[g >> 11][(g >> 6) & (CO - 1)][g & (CI - 1)] = weight[g];
  }
  __syncthreads();
  const int k4 = lane >> 2;
  const int m4 = lane & 3;
  const int o = lane & 31;
  const int hh = lane >> 5;
  const float cm = cvec[m4];
  const float bo = bias[o];
  for (int g = blockIdx.x; g < BN / 4; g += gridDim.x) {
    const int bn = g * 4 + wv;
    const int b = (bn >= NN) ? 1 : 0;
    const int* adjp = adj + (size_t)bn * KK;
    const float* xb = x + (size_t)b * NN * CI;
    int4 A[4];
#pragma unroll
    for (int i = 0; i < 4; ++i) A[i] = ((const int4*)adjp)[i];
    int deg = 0;
#pragma unroll
    for (int i = 0; i < 4; ++i)
      deg += (A[i].x != 0) + (A[i].y != 0) + (A[i].z != 0) + (A[i].w != 0);
    const float inv_deg = (deg > 0) ? 1.0f / (float)deg : 0.0f;
    int a = adjp[k4];
    float vg = 0.f;
    if (a != 0) vg = vx[((size_t)b * NN + (a - 1)) * MM + m4];
    float logit = vg + ux[(size_t)bn * MM + m4] + cm;
    float mx = fmaxf(logit, __shfl_xor(logit, 1));
    mx = fmaxf(mx, __shfl_xor(mx, 2));
    float e = __expf(logit - mx);
    float s = e + __shfl_xor(e, 1);
    s += __shfl_xor(s, 2);
    q_lds2[wv][lane] = (a != 0) ? (e / s) : 0.f;
    int rows[KK];
    {
      int tmp[KK] = {A[0].x, A[0].y, A[0].z, A[0].w, A[1].x, A[1].y,
                     A[1].z, A[1].w, A[2].x, A[2].y, A[2].z, A[2].w,
                     A[3].x, A[3].y, A[3].z, A[3].w};
#pragma unroll
      for (int k = 0; k < KK; ++k) rows[k] = max(tmp[k], 1) - 1;
    }
    float xg[KK];
#pragma unroll
    for (int k = 0; k < KK; ++k) xg[k] = xb[(size_t)rows[k] * CI + lane];
    float t0 = 0.f, t1 = 0.f, t2 = 0.f, t3 = 0.f;
#pragma unroll
    for (int k = 0; k < KK; ++k) {
      float4 qv = *(const float4*)&q_lds2[wv][k * 4];
      t0 += qv.x * xg[k];
      t1 += qv.y * xg[k];
      t2 += qv.z * xg[k];
      t3 += qv.w * xg[k];
    }
    t_lds2[wv][0][lane] = t0;
    t_lds2[wv][1][lane] = t1;
    t_lds2[wv][2][lane] = t2;
    t_lds2[wv][3][lane] = t3;
    float a0 = 0.f, a1 = 0.f, a2 = 0.f, a3 = 0.f;
#pragma unroll
    for (int mm = 0; mm < 2; ++mm) {
      const float* wrow = &w_lds2[2 * hh + mm][o][0];
      const float* trow = &t_lds2[wv][2 * hh + mm][0];
#pragma unroll
      for (int t4 = 0; t4 < CI / 4; ++t4) {
        float4 wvv = *(const float4*)(wrow + 4 * t4);
        float4 tv = *(const float4*)(trow + 4 * t4);
        a0 += wvv.x * tv.x;
        a1 += wvv.y * tv.y;
        a2 += wvv.z * tv.z;
        a3 += wvv.w * tv.w;
      }
    }
    float acc = (a0 + a1) + (a2 + a3);
    acc += __shfl_xor(acc, 32);
    if (lane < 32) out[(size_t)bn * CO + o] = acc * inv_deg + bo;
  }
}

extern "C" void kernel_launch(void* const* d_in, const int* in_sizes, int n_in,
                              void* d_out, int out_size, void* d_ws,
                              size_t ws_size, hipStream_t stream) {
  const float* x = (const float*)d_in[0];
  const int* adj = (const int*)d_in[1];
  const float* weight = (const float*)d_in[2];
  const float* bias = (const float*)d_in[3];
  const float* u = (const float*)d_in[4];
  const float* v = (const float*)d_in[5];
  const float* cvec = (const float*)d_in[6];
  float* out = (float*)d_out;

  float* ux = (float*)d_ws;          // BN*4 f32
  float* vx = ux + (size_t)BN * MM;  // BN*4 f32
  const size_t base = (size_t)BN * MM * 2 * sizeof(float);           // 3.2 MB
  const size_t xh_bytes = (size_t)BN * CI * sizeof(unsigned short);  // 12.8 MB

  if (ws_size >= base + xh_bytes) {
    unsigned short* xhb = (unsigned short*)((char*)d_ws + base);
    k_prep2<<<1563, 256, 0, stream>>>(x, u, v, ux, vx, xhb);
    k_gather<<<GRID, 256, 0, stream>>>(xhb, adj, weight, bias, cvec, ux, vx,
                                       out);
  } else {
    k_uxvx<<<(BN + 255) / 256, 256, 0, stream>>>(x, u, v, ux, vx);
    k_main_old<<<1024, 256, 0, stream>>>(x, adj, weight, bias, cvec, ux, vx,
                                         out);
  }
}

// Round 18
// 62.204 us; speedup vs baseline: 1.0216x; 1.0216x over previous
//
#include <hip/hip_runtime.h>

namespace {
constexpr int BB = 2;
constexpr int NN = 50000;
constexpr int KK = 16;
constexpr int CI = 64;
constexpr int CO = 32;
constexpr int MM = 4;
constexpr int BN = BB * NN;       // 100000 nodes
constexpr int GROUPS2 = NN / 2;   // 25000 2-node groups per batch
constexpr int GRID = 768;         // 3 blocks/CU (52KB LDS)
constexpr int WAVES = (GRID / 2) * 4;  // 1536 waves per batch
}

typedef __attribute__((ext_vector_type(8))) short short8v;
typedef __attribute__((ext_vector_type(4))) float float4v;
typedef __attribute__((ext_vector_type(2))) float f32x2;

__device__ __forceinline__ unsigned short bf16r(float f) {
  unsigned int u = __float_as_uint(f);
  u += 0x7FFFu + ((u >> 16) & 1u);
  return (unsigned short)(u >> 16);
}

// K1: wave-per-16-node tile. Coalesced x loads; ux/vx via 2 MFMAs against
// [u;v] B-fragment; bf16 xh written from the same registers.
__global__ __launch_bounds__(256) void k_prep2(
    const float* __restrict__ x, const float* __restrict__ u,
    const float* __restrict__ v, float* __restrict__ ux,
    float* __restrict__ vx, unsigned short* __restrict__ xh) {
  const int tid = threadIdx.x;
  const int lane = tid & 63;
  const int wv = tid >> 6;
  const int col = lane & 15;
  const int krow = lane >> 4;

  short8v bfrag2[2];
#pragma unroll
  for (int ks = 0; ks < 2; ++ks)
#pragma unroll
    for (int e = 0; e < 8; ++e) {
      int c = ks * 32 + krow * 8 + e;
      float val = (col < 4) ? u[col * CI + c]
                            : ((col < 8) ? v[(col - 4) * CI + c] : 0.f);
      bfrag2[ks][e] = (short)bf16r(val);
    }

  const float4v zero = {0.f, 0.f, 0.f, 0.f};
  const int nw = gridDim.x * 4;
  for (int t = blockIdx.x * 4 + wv; t < BN / 16; t += nw) {
    const int n0 = t * 16;
    const float* xp = x + (size_t)(n0 + col) * CI + krow * 8;
    short8v afrag[2];
    uint4 hpack[2];
#pragma unroll
    for (int ks = 0; ks < 2; ++ks) {
      float4 lo = *(const float4*)(xp + ks * 32);
      float4 hi = *(const float4*)(xp + ks * 32 + 4);
      unsigned short h0 = bf16r(lo.x), h1 = bf16r(lo.y);
      unsigned short h2 = bf16r(lo.z), h3 = bf16r(lo.w);
      unsigned short h4 = bf16r(hi.x), h5 = bf16r(hi.y);
      unsigned short h6 = bf16r(hi.z), h7 = bf16r(hi.w);
      afrag[ks][0] = (short)h0;
      afrag[ks][1] = (short)h1;
      afrag[ks][2] = (short)h2;
      afrag[ks][3] = (short)h3;
      afrag[ks][4] = (short)h4;
      afrag[ks][5] = (short)h5;
      afrag[ks][6] = (short)h6;
      afrag[ks][7] = (short)h7;
      hpack[ks] = make_uint4((unsigned)h0 | ((unsigned)h1 << 16),
                             (unsigned)h2 | ((unsigned)h3 << 16),
                             (unsigned)h4 | ((unsigned)h5 << 16),
                             (unsigned)h6 | ((unsigned)h7 << 16));
    }
    unsigned short* xo = xh + (size_t)(n0 + col) * CI + krow * 8;
    *(uint4*)(xo) = hpack[0];
    *(uint4*)(xo + 32) = hpack[1];

    float4v acc2 = zero;
    acc2 = __builtin_amdgcn_mfma_f32_16x16x32_bf16(afrag[0], bfrag2[0], acc2,
                                                   0, 0, 0);
    acc2 = __builtin_amdgcn_mfma_f32_16x16x32_bf16(afrag[1], bfrag2[1], acc2,
                                                   0, 0, 0);
#pragma unroll
    for (int ri = 0; ri < 4; ++ri) {
      int node = n0 + krow * 4 + ri;
      if (col < 4)
        ux[(size_t)node * MM + col] = acc2[ri];
      else if (col < 8)
        vx[(size_t)node * MM + (col - 4)] = acc2[ri];
    }
  }
}

// K2: per 2-node iteration: 4x dwordx4 gathers (8 rows/instr) -> LDS x-tile;
// vg = X·V^T via MFMA (no vx gather requests!); softmax; ACC from LDS;
// MFMA W-epilogue. Deg-norm folded into q.
__global__ __launch_bounds__(256, 3) void k_gather(
    const unsigned short* __restrict__ xh, const int* __restrict__ adj,
    const float* __restrict__ weight, const float* __restrict__ bias,
    const float* __restrict__ cvec, const float* __restrict__ ux,
    const float* __restrict__ v, float* __restrict__ out) {
  __shared__ unsigned short w_lds[8192];     // 16 KB W B-fragments
  __shared__ unsigned short t_lds[4][2048];  // 16 KB t rows (8x256 per wave)
  __shared__ unsigned short xtile[4][2048];  // 16 KB x-tiles (32x64 per wave)
  __shared__ float q_lds[4][2][64];          // 2 KB
  __shared__ float vgscr[4][2][64];          // 2 KB

  const int tid = threadIdx.x;
  const int lane = tid & 63;
  const int wv = tid >> 6;

  // Stage W as MFMA B-fragments (k = c*4+m ordering, o = tl*16+(l&15))
  for (int i = tid; i < 2 * 8 * 64; i += 256) {
    int tl = i >> 9;
    int ks = (i >> 6) & 7;
    int l = i & 63;
    int o = tl * 16 + (l & 15);
    unsigned pk[4];
#pragma unroll
    for (int ee = 0; ee < 4; ++ee) {
      int k0 = ks * 32 + (l >> 4) * 8 + 2 * ee;
      unsigned lo = bf16r(weight[((k0 & 3) * CO + o) * CI + (k0 >> 2)]);
      unsigned hi =
          bf16r(weight[(((k0 + 1) & 3) * CO + o) * CI + ((k0 + 1) >> 2)]);
      pk[ee] = lo | (hi << 16);
    }
    *(uint4*)&w_lds[i * 8] = make_uint4(pk[0], pk[1], pk[2], pk[3]);
  }

  // v as MFMA B-fragment: col<4 -> v[col][c], else 0 (k = ks*32+(l>>4)*8+e)
  const int col = lane & 15;
  const int krow = lane >> 4;
  short8v vfrag[2];
#pragma unroll
  for (int ks = 0; ks < 2; ++ks)
#pragma unroll
    for (int e = 0; e < 8; ++e) {
      int c = ks * 32 + krow * 8 + e;
      vfrag[ks][e] = (short)((col < 4) ? bf16r(v[col * CI + c]) : 0);
    }
  __syncthreads();

  const int m4 = lane & 3;
  const int k4 = lane >> 2;
  const float cm = cvec[m4];
  const float b0 = bias[lane & 15];
  const float b1 = bias[16 + (lane & 15)];
  const int hn = lane >> 5;   // half-wave node id
  const int c2 = lane & 31;   // channel-pair index

  // XCD partition: XCDs 0-3 -> batch 0, 4-7 -> batch 1
  const int xcd = blockIdx.x & 7;
  const int b = xcd >> 2;
  const int wb = ((blockIdx.x >> 3) << 2) | (xcd & 3);
  const int w = wb * 4 + wv;
  const size_t bbase = (size_t)b * NN;
  const unsigned short* xhb = xh + bbase * CI;
  unsigned short* twv = t_lds[wv];
  char* xt = (char*)&xtile[wv][0];
  float* vs = &vgscr[wv][0][0];

  // loop-invariant addressing
  const int bpb = (lane >> 3) << 2;                 // bpermute idx base (row*4)
  const unsigned chunkoff = (unsigned)((lane & 7) * 16);
  const unsigned swoff =                            // stage write (row=lane>>3)
      (unsigned)((lane >> 3) * 128) +
      (chunkoff ^ (unsigned)((lane >> 3) << 4));
  unsigned vga[2][2];                               // vg A-frag read addrs
#pragma unroll
  for (int t2 = 0; t2 < 2; ++t2)
#pragma unroll
    for (int ks = 0; ks < 2; ++ks)
      vga[t2][ks] =
          (unsigned)((t2 * 16 + (lane & 15)) * 128) +
          ((((unsigned)(ks * 4 + (lane >> 4)) ^ (unsigned)(lane & 7)) << 4));
  unsigned xav[8];                                  // ACC read offsets
#pragma unroll
  for (int j = 0; j < 8; ++j)
    xav[j] = ((((unsigned)(c2 >> 2) ^ (unsigned)j) << 4) |
              ((unsigned)(c2 & 3) << 2));
  const unsigned sw2 = (unsigned)((lane >> 4) * 64 + (lane & 15) * 4);

// 16 MFMAs over 8 staged t-rows; store valid (iteration, parity) nodes
#define FLUSH2(JC)                                                         \
  {                                                                       \
    float4v ac0 = {0.f, 0.f, 0.f, 0.f};                                   \
    float4v ac1 = {0.f, 0.f, 0.f, 0.f};                                   \
    const int arow = lane & 7;                                            \
    const unsigned axor = (unsigned)(arow & 7) << 4;                      \
    _Pragma("unroll") for (int ks = 0; ks < 8; ++ks) {                    \
      unsigned aoff =                                                     \
          (unsigned)arow * 512u +                                         \
          ((((unsigned)(lane >> 4)) * 16u + (unsigned)ks * 64u) ^ axor);  \
      short8v A = *(const short8v*)((const char*)twv + aoff);             \
      short8v Bl = *(const short8v*)&w_lds[(0 * 8 + ks) * 512 + lane * 8];\
      short8v Bh = *(const short8v*)&w_lds[(1 * 8 + ks) * 512 + lane * 8];\
      ac0 = __builtin_amdgcn_mfma_f32_16x16x32_bf16(A, Bl, ac0, 0, 0, 0); \
      ac1 = __builtin_amdgcn_mfma_f32_16x16x32_bf16(A, Bh, ac1, 0, 0, 0); \
    }                                                                     \
    int jj = lane >> 4;                                                   \
    _Pragma("unroll") for (int ri = 0; ri < 4; ++ri) {                    \
      int it = jj * 2 + (ri >> 1);                                        \
      int gg = gbase + it * WAVES;                                        \
      if (it < (JC) && gg < GROUPS2) {                                    \
        size_t node = bbase + (size_t)gg * 2 + (ri & 1);                  \
        out[node * CO + (lane & 15)] = ac0[ri] + b0;                      \
        out[node * CO + 16 + (lane & 15)] = ac1[ri] + b1;                 \
      }                                                                   \
    }                                                                     \
  }

  int g = w;
  int av = 0;
  if (g < GROUPS2) av = adj[(bbase + (size_t)g * 2) * KK + (lane & 31)];
  int jrows = 0;
  int gbase = g;

  while (g < GROUPS2) {
    const int av_c = av;
    const size_t bn0 = bbase + (size_t)g * 2;

    // softmax-side masks + center terms
    const int as0 = __shfl(av_c, k4);
    const int as1 = __shfl(av_c, 16 + k4);
    const float ux0 = ux[bn0 * MM + m4];
    const float ux1 = ux[bn0 * MM + MM + m4];

    // gather 32 neighbor rows: 4 instrs, 8 rows each (per-lane vaddr)
    uint4 gx0, gx1, gx2, gx3;
    {
      int nb0 = __builtin_amdgcn_ds_bpermute(bpb + 0, av_c);
      int nb1 = __builtin_amdgcn_ds_bpermute(bpb + 32, av_c);
      int nb2 = __builtin_amdgcn_ds_bpermute(bpb + 64, av_c);
      int nb3 = __builtin_amdgcn_ds_bpermute(bpb + 96, av_c);
      unsigned r0 = (unsigned)(max(nb0, 1) - 1) * 128u + chunkoff;
      unsigned r1 = (unsigned)(max(nb1, 1) - 1) * 128u + chunkoff;
      unsigned r2 = (unsigned)(max(nb2, 1) - 1) * 128u + chunkoff;
      unsigned r3 = (unsigned)(max(nb3, 1) - 1) * 128u + chunkoff;
      gx0 = *(const uint4*)((const char*)xhb + (size_t)r0);
      gx1 = *(const uint4*)((const char*)xhb + (size_t)r1);
      gx2 = *(const uint4*)((const char*)xhb + (size_t)r2);
      gx3 = *(const uint4*)((const char*)xhb + (size_t)r3);
    }

    // prefetch next iteration's adjacency
    const int gn = g + WAVES;
    if (gn < GROUPS2) av = adj[(bbase + (size_t)gn * 2) * KK + (lane & 31)];

    // stage rows into swizzled x-tile (compiler inserts vmcnt before writes)
    *(uint4*)(xt + swoff + 0) = gx0;
    *(uint4*)(xt + swoff + 1024) = gx1;
    *(uint4*)(xt + swoff + 2048) = gx2;
    *(uint4*)(xt + swoff + 3072) = gx3;

    // vg = X(32x64) . v^T via MFMA (2 tiles of 16 rows)
    {
      short8v A00 = *(const short8v*)(xt + vga[0][0]);
      short8v A01 = *(const short8v*)(xt + vga[0][1]);
      short8v A10 = *(const short8v*)(xt + vga[1][0]);
      short8v A11 = *(const short8v*)(xt + vga[1][1]);
      float4v vac0 = {0.f, 0.f, 0.f, 0.f};
      float4v vac1 = {0.f, 0.f, 0.f, 0.f};
      vac0 = __builtin_amdgcn_mfma_f32_16x16x32_bf16(A00, vfrag[0], vac0, 0,
                                                     0, 0);
      vac0 = __builtin_amdgcn_mfma_f32_16x16x32_bf16(A01, vfrag[1], vac0, 0,
                                                     0, 0);
      vac1 = __builtin_amdgcn_mfma_f32_16x16x32_bf16(A10, vfrag[0], vac1, 0,
                                                     0, 0);
      vac1 = __builtin_amdgcn_mfma_f32_16x16x32_bf16(A11, vfrag[1], vac1, 0,
                                                     0, 0);
      // scatter D (col=lane&15=m, row=(lane>>4)*4+reg) -> softmax lane order
      if ((lane & 15) < 4) {
        *(float*)((char*)vs + sw2 + 0) = vac0[0];
        *(float*)((char*)vs + sw2 + 16) = vac0[1];
        *(float*)((char*)vs + sw2 + 32) = vac0[2];
        *(float*)((char*)vs + sw2 + 48) = vac0[3];
        *(float*)((char*)vs + sw2 + 256) = vac1[0];
        *(float*)((char*)vs + sw2 + 272) = vac1[1];
        *(float*)((char*)vs + sw2 + 288) = vac1[2];
        *(float*)((char*)vs + sw2 + 304) = vac1[3];
      }
    }
    const float vg0 = vgscr[wv][0][lane];
    const float vg1 = vgscr[wv][1][lane];

    // softmax for 2 nodes; deg-norm folded into q
    {
      const unsigned msk = (unsigned)__ballot(av_c != 0);
      int d0 = __popc(msk & 0xFFFFu);
      int d1 = __popc(msk >> 16);
      float i0 = d0 ? __builtin_amdgcn_rcpf((float)d0) : 0.f;
      float i1 = d1 ? __builtin_amdgcn_rcpf((float)d1) : 0.f;
      float e0 = __expf(vg0 + ux0 + cm);
      float e1 = __expf(vg1 + ux1 + cm);
      float s0 = e0 + __shfl_xor(e0, 1);
      float s1 = e1 + __shfl_xor(e1, 1);
      s0 += __shfl_xor(s0, 2);
      s1 += __shfl_xor(s1, 2);
      q_lds[wv][0][lane] =
          (as0 != 0) ? e0 * __builtin_amdgcn_rcpf(s0) * i0 : 0.f;
      q_lds[wv][1][lane] =
          (as1 != 0) ? e1 * __builtin_amdgcn_rcpf(s1) * i1 : 0.f;
    }
    // same-wave DS write->read is in-order: no barrier needed

    // ACC: half-wave per node, lane owns channel pair (2*c2, 2*c2+1)
    {
      const float4* qp = (const float4*)&q_lds[wv][hn][0];
      f32x2 a0 = {0.f, 0.f}, a1 = {0.f, 0.f};
      f32x2 a2 = {0.f, 0.f}, a3 = {0.f, 0.f};
#pragma unroll
      for (int k = 0; k < KK; ++k) {
        unsigned xx =
            *(const unsigned*)(xt + hn * 2048 + k * 128 + xav[k & 7]);
        float xe = __uint_as_float(xx << 16);
        float xo = __uint_as_float(xx & 0xFFFF0000u);
        f32x2 xp = {xe, xo};
        float4 qv = qp[k];
        a0 += xp * qv.x;
        a1 += xp * qv.y;
        a2 += xp * qv.z;
        a3 += xp * qv.w;
      }
      unsigned p0, p1, p2, p3;
      asm("v_cvt_pk_bf16_f32 %0, %1, %2" : "=v"(p0) : "v"(a0[0]), "v"(a1[0]));
      asm("v_cvt_pk_bf16_f32 %0, %1, %2" : "=v"(p1) : "v"(a2[0]), "v"(a3[0]));
      asm("v_cvt_pk_bf16_f32 %0, %1, %2" : "=v"(p2) : "v"(a0[1]), "v"(a1[1]));
      asm("v_cvt_pk_bf16_f32 %0, %1, %2" : "=v"(p3) : "v"(a2[1]), "v"(a3[1]));
      const int trow = jrows * 2 + hn;
      unsigned boff = (unsigned)trow * 512u +
                      (((unsigned)c2 * 16u) ^ ((unsigned)(trow & 7) << 4));
      *(uint4*)((char*)twv + boff) = make_uint4(p0, p1, p2, p3);
    }

    ++jrows;
    g = gn;
    if (jrows == 4) {
      FLUSH2(4)
      jrows = 0;
      gbase = g;
    }
  }
  if (jrows > 0) FLUSH2(jrows)
}

// ---------- fallback path (ws too small): all-fp32 ----------
__global__ __launch_bounds__(256) void k_uxvx(
    const float* __restrict__ x, const float* __restrict__ u,
    const float* __restrict__ v, float* __restrict__ ux,
    float* __restrict__ vx) {
  int idx = blockIdx.x * 256 + threadIdx.x;
  if (idx >= BN) return;
  const float4* xr = (const float4*)(x + (size_t)idx * CI);
  float su[MM] = {0.f, 0.f, 0.f, 0.f};
  float sv[MM] = {0.f, 0.f, 0.f, 0.f};
#pragma unroll
  for (int t = 0; t < CI / 4; ++t) {
    float4 xv = xr[t];
#pragma unroll
    for (int m = 0; m < MM; ++m) {
      float4 uv = *(const float4*)(u + m * CI + t * 4);
      float4 vv = *(const float4*)(v + m * CI + t * 4);
      su[m] += uv.x * xv.x + uv.y * xv.y + uv.z * xv.z + uv.w * xv.w;
      sv[m] += vv.x * xv.x + vv.y * xv.y + vv.z * xv.z + vv.w * xv.w;
    }
  }
  ((float4*)ux)[idx] = make_float4(su[0], su[1], su[2], su[3]);
  ((float4*)vx)[idx] = make_float4(sv[0], sv[1], sv[2], sv[3]);
}

__global__ __launch_bounds__(256) void k_main_old(
    const float* __restrict__ x, const int* __restrict__ adj,
    const float* __restrict__ weight, const float* __restrict__ bias,
    const float* __restrict__ cvec, const float* __restrict__ ux,
    const float* __restrict__ vx, float* __restrict__ out) {
  __shared__ float w_lds2[MM][CO][CI + 4];
  __shared__ float q_lds2[4][64];
  __shared__ float t_lds2[4][MM][CI];
  const int tid = threadIdx.x;
  const int lane = tid & 63;
  const int wv = tid >> 6;
#pragma unroll
  for (int i = 0; i < (MM * CO * CI) / 256; ++i) {
    int g = i * 256 + tid;
    w_lds2[g >> 11][(g >> 6) & (CO - 1)][g & (CI - 1)] = weight[g];
  }
  __syncthreads();
  const int k4 = lane >> 2;
  const int m4 = lane & 3;
  const int o = lane & 31;
  const int hh = lane >> 5;
  const float cm = cvec[m4];
  const float bo = bias[o];
  for (int g = blockIdx.x; g < BN / 4; g += gridDim.x) {
    const int bn = g * 4 + wv;
    const int b = (bn >= NN) ? 1 : 0;
    const int* adjp = adj + (size_t)bn * KK;
    const float* xb = x + (size_t)b * NN * CI;
    int4 A[4];
#pragma unroll
    for (int i = 0; i < 4; ++i) A[i] = ((const int4*)adjp)[i];
    int deg = 0;
#pragma unroll
    for (int i = 0; i < 4; ++i)
      deg += (A[i].x != 0) + (A[i].y != 0) + (A[i].z != 0) + (A[i].w != 0);
    const float inv_deg = (deg > 0) ? 1.0f / (float)deg : 0.0f;
    int a = adjp[k4];
    float vg = 0.f;
    if (a != 0) vg = vx[((size_t)b * NN + (a - 1)) * MM + m4];
    float logit = vg + ux[(size_t)bn * MM + m4] + cm;
    float mx = fmaxf(logit, __shfl_xor(logit, 1));
    mx = fmaxf(mx, __shfl_xor(mx, 2));
    float e = __expf(logit - mx);
    float s = e + __shfl_xor(e, 1);
    s += __shfl_xor(s, 2);
    q_lds2[wv][lane] = (a != 0) ? (e / s) : 0.f;
    int rows[KK];
    {
      int tmp[KK] = {A[0].x, A[0].y, A[0].z, A[0].w, A[1].x, A[1].y,
                     A[1].z, A[1].w, A[2].x, A[2].y, A[2].z, A[2].w,
                     A[3].x, A[3].y, A[3].z, A[3].w};
#pragma unroll
      for (int k = 0; k < KK; ++k) rows[k] = max(tmp[k], 1) - 1;
    }
    float xg[KK];
#pragma unroll
    for (int k = 0; k < KK; ++k) xg[k] = xb[(size_t)rows[k] * CI + lane];
    float t0 = 0.f, t1 = 0.f, t2 = 0.f, t3 = 0.f;
#pragma unroll
    for (int k = 0; k < KK; ++k) {
      float4 qv = *(const float4*)&q_lds2[wv][k * 4];
      t0 += qv.x * xg[k];
      t1 += qv.y * xg[k];
      t2 += qv.z * xg[k];
      t3 += qv.w * xg[k];
    }
    t_lds2[wv][0][lane] = t0;
    t_lds2[wv][1][lane] = t1;
    t_lds2[wv][2][lane] = t2;
    t_lds2[wv][3][lane] = t3;
    float a0 = 0.f, a1 = 0.f, a2 = 0.f, a3 = 0.f;
#pragma unroll
    for (int mm = 0; mm < 2; ++mm) {
      const float* wrow = &w_lds2[2 * hh + mm][o][0];
      const float* trow = &t_lds2[wv][2 * hh + mm][0];
#pragma unroll
      for (int t4 = 0; t4 < CI / 4; ++t4) {
        float4 wvv = *(const float4*)(wrow + 4 * t4);
        float4 tv = *(const float4*)(trow + 4 * t4);
        a0 += wvv.x * tv.x;
        a1 += wvv.y * tv.y;
        a2 += wvv.z * tv.z;
        a3 += wvv.w * tv.w;
      }
    }
    float acc = (a0 + a1) + (a2 + a3);
    acc += __shfl_xor(acc, 32);
    if (lane < 32) out[(size_t)bn * CO + o] = acc * inv_deg + bo;
  }
}

extern "C" void kernel_launch(void* const* d_in, const int* in_sizes, int n_in,
                              void* d_out, int out_size, void* d_ws,
                              size_t ws_size, hipStream_t stream) {
  const float* x = (const float*)d_in[0];
  const int* adj = (const int*)d_in[1];
  const float* weight = (const float*)d_in[2];
  const float* bias = (const float*)d_in[3];
  const float* u = (const float*)d_in[4];
  const float* v = (const float*)d_in[5];
  const float* cvec = (const float*)d_in[6];
  float* out = (float*)d_out;

  float* ux = (float*)d_ws;          // BN*4 f32
  float* vx = ux + (size_t)BN * MM;  // BN*4 f32
  const size_t base = (size_t)BN * MM * 2 * sizeof(float);           // 3.2 MB
  const size_t xh_bytes = (size_t)BN * CI * sizeof(unsigned short);  // 12.8 MB

  if (ws_size >= base + xh_bytes) {
    unsigned short* xhb = (unsigned short*)((char*)d_ws + base);
    k_prep2<<<1563, 256, 0, stream>>>(x, u, v, ux, vx, xhb);
    k_gather<<<GRID, 256, 0, stream>>>(xhb, adj, weight, bias, cvec, ux, v,
                                       out);
  } else {
    k_uxvx<<<(BN + 255) / 256, 256, 0, stream>>>(x, u, v, ux, vx);
    k_main_old<<<1024, 256, 0, stream>>>(x, adj, weight, bias, cvec, ux, vx,
                                         out);
  }
}